// Round 1
// 2071.959 us; speedup vs baseline: 1.5363x; 1.5363x over previous
//
#include <hip/hip_runtime.h>
#include <math.h>

#define BDIM 65536
#define HDIM 4096
#define RDIM 256
#define EDIM 64
#define OUT_W_OFF (BDIM * 2)

using f16x8 = __attribute__((ext_vector_type(8))) _Float16;
using f32x4 = __attribute__((ext_vector_type(4))) float;

#define LO_SCALE 1024.0f
#define LO_INV   0.0009765625f   // 1/1024, exact

// ---------------------------------------------------------------------------
// Kernel 1: x_proj = x @ Wp + bp   (M=65536, K=4096, N=256)
// Split-f16 3-pass MFMA: x = hi + lo/1024 (f16), W likewise.
//   acc  += Ah*Bh          (per-term err ~2^-22 after recombine)
//   acc2 += Al*Bh + Ah*Bl  (lo pre-scaled by 1024 to stay f16-normal)
//   out   = acc + acc2/1024
// BM=128, BN=256 (full N so X is fetched once), BK=32, 512 thr = 8 waves,
// wave tile 64x64 = 4x4 fragments of mfma_f32_16x16x32_f16.
// LDS tiles stored [row][k] / [col][k] (K-contiguous per MFMA lane),
// pitch 40 halfs (80 B = 20 dwords -> 2-way-max bank pattern, 16B aligned).
// ---------------------------------------------------------------------------
__global__ __launch_bounds__(512, 2) void k_xproj(
    const float* __restrict__ X, const float* __restrict__ Wp,
    const float* __restrict__ bp, float* __restrict__ XP)
{
    __shared__ _Float16 sAh[128][40];
    __shared__ _Float16 sAl[128][40];
    __shared__ _Float16 sBh[256][40];
    __shared__ _Float16 sBl[256][40];

    const int tid  = threadIdx.x;
    const int lane = tid & 63;
    const int wid  = tid >> 6;
    const int wm   = wid >> 2;          // 0..1 : wave row block (64 rows)
    const int wn   = wid & 3;           // 0..3 : wave col block (64 cols)
    const int row0 = blockIdx.x * 128;

    const int aRowF = lane & 15;        // row/col within 16-tile
    const int kg8   = (lane >> 4) * 8;  // k offset within BK=32

    // staging assignments
    const int xRow = tid >> 2;          // 0..127
    const int xK   = (tid & 3) * 8;     // 0,8,16,24
    const int wCol = tid & 255;         // 0..255
    const int wK0  = (tid >> 8) * 16;   // 0 or 16

    f32x4 acc[4][4], acc2[4][4];
#pragma unroll
    for (int i = 0; i < 4; ++i)
#pragma unroll
        for (int j = 0; j < 4; ++j) {
            acc[i][j]  = (f32x4){0.0f, 0.0f, 0.0f, 0.0f};
            acc2[i][j] = (f32x4){0.0f, 0.0f, 0.0f, 0.0f};
        }

    const float* xPtr = X + (size_t)(row0 + xRow) * HDIM + xK;
    const float* wPtr = Wp + (size_t)wK0 * RDIM + wCol;

    // prefetch tile 0
    float4 px0 = *(const float4*)(xPtr);
    float4 px1 = *(const float4*)(xPtr + 4);
    float pw[16];
#pragma unroll
    for (int i = 0; i < 16; ++i) pw[i] = wPtr[i * RDIM];

    const int NT = HDIM / 32;   // 128 k-tiles
    for (int kt = 0; kt < NT; ++kt) {
        // ---- convert prefetched fp32 -> split f16, store to LDS ----
        {
            float xv[8] = {px0.x, px0.y, px0.z, px0.w, px1.x, px1.y, px1.z, px1.w};
            f16x8 hv, lv;
#pragma unroll
            for (int j = 0; j < 8; ++j) {
                const float v = xv[j];
                const _Float16 h = (_Float16)v;
                hv[j] = h;
                lv[j] = (_Float16)((v - (float)h) * LO_SCALE);
            }
            *(f16x8*)(&sAh[xRow][xK]) = hv;
            *(f16x8*)(&sAl[xRow][xK]) = lv;

            f16x8 wh0, wl0, wh1, wl1;
#pragma unroll
            for (int j = 0; j < 8; ++j) {
                float v = pw[j];
                _Float16 h = (_Float16)v;
                wh0[j] = h;
                wl0[j] = (_Float16)((v - (float)h) * LO_SCALE);
                v = pw[8 + j];
                h = (_Float16)v;
                wh1[j] = h;
                wl1[j] = (_Float16)((v - (float)h) * LO_SCALE);
            }
            *(f16x8*)(&sBh[wCol][wK0])     = wh0;
            *(f16x8*)(&sBh[wCol][wK0 + 8]) = wh1;
            *(f16x8*)(&sBl[wCol][wK0])     = wl0;
            *(f16x8*)(&sBl[wCol][wK0 + 8]) = wl1;
        }
        __syncthreads();

        // ---- issue next-tile global loads (latency hides under MFMA) ----
        if (kt + 1 < NT) {
            const float* xp2 = xPtr + (size_t)(kt + 1) * 32;
            px0 = *(const float4*)(xp2);
            px1 = *(const float4*)(xp2 + 4);
            const float* wp2 = wPtr + (size_t)(kt + 1) * 32 * RDIM;
#pragma unroll
            for (int i = 0; i < 16; ++i) pw[i] = wp2[i * RDIM];
        }

        // ---- fragments + 3-pass MFMA ----
        f16x8 Bh[4], Bl[4];
#pragma unroll
        for (int nt = 0; nt < 4; ++nt) {
            const int bc = wn * 64 + nt * 16 + aRowF;
            Bh[nt] = *(const f16x8*)(&sBh[bc][kg8]);
            Bl[nt] = *(const f16x8*)(&sBl[bc][kg8]);
        }
#pragma unroll
        for (int mt = 0; mt < 4; ++mt) {
            const int ar = wm * 64 + mt * 16 + aRowF;
            const f16x8 Ah = *(const f16x8*)(&sAh[ar][kg8]);
            const f16x8 Al = *(const f16x8*)(&sAl[ar][kg8]);
#pragma unroll
            for (int nt = 0; nt < 4; ++nt) {
                acc[mt][nt]  = __builtin_amdgcn_mfma_f32_16x16x32_f16(Ah, Bh[nt], acc[mt][nt],  0, 0, 0);
                acc2[mt][nt] = __builtin_amdgcn_mfma_f32_16x16x32_f16(Al, Bh[nt], acc2[mt][nt], 0, 0, 0);
                acc2[mt][nt] = __builtin_amdgcn_mfma_f32_16x16x32_f16(Ah, Bl[nt], acc2[mt][nt], 0, 0, 0);
            }
        }
        __syncthreads();
    }

    // ---- epilogue: recombine, +bp, store ----
    // C/D layout (verified): col = lane&15, row = (lane>>4)*4 + reg
    float bpv[4];
#pragma unroll
    for (int nt = 0; nt < 4; ++nt) bpv[nt] = bp[wn * 64 + nt * 16 + aRowF];
    const int rBase = row0 + wm * 64 + (lane >> 4) * 4;
#pragma unroll
    for (int mt = 0; mt < 4; ++mt) {
#pragma unroll
        for (int j = 0; j < 4; ++j) {
            const int r = rBase + mt * 16 + j;
            float* rowp = XP + (size_t)r * RDIM + wn * 64 + aRowF;
#pragma unroll
            for (int nt = 0; nt < 4; ++nt)
                rowp[nt * 16] = acc[mt][nt][j] + LO_INV * acc2[mt][nt][j] + bpv[nt];
        }
    }
}

// ---------------------------------------------------------------------------
// Kernel 2: t = h@A + xp@Bm ; h_new = h + 0.1*(-h/tau + tanh(t))
// Written in-place over XP (block owns full 256-col rows -> race-free).
// BM=64, BN=256 (full), K=512 (two phases of 256), 256 threads, 8x8 micro.
// ---------------------------------------------------------------------------
__global__ __launch_bounds__(256) void k_cfc(
    const float* __restrict__ H, const float* __restrict__ Amat,
    const float* __restrict__ Bmat, const float* __restrict__ tau,
    float* __restrict__ XP)
{
    __shared__ float sI[16][64];    // k-major input tile
    __shared__ float sW[16][256];   // k-major weight tile
    const int tid  = threadIdx.x;
    const int row0 = blockIdx.x * 64;
    const int wr = tid >> 5, wc = tid & 31;   // 8 x 32 thread grid
    const int mBase = wr * 8, nBase = wc * 8;

    const int iRow = tid >> 2;        // 0..63
    const int iK   = (tid & 3) * 4;   // 0,4,8,12

    float acc[8][8];
#pragma unroll
    for (int i = 0; i < 8; ++i)
#pragma unroll
        for (int j = 0; j < 8; ++j) acc[i][j] = 0.0f;

    float4 pi, pw[4];
    // prefetch tile 0 (phase 0: IN=H, W=Amat)
    pi = *(const float4*)(H + (size_t)(row0 + iRow) * RDIM + iK);
#pragma unroll
    for (int i = 0; i < 4; ++i) {
        const int idx = tid + i * 256;
        const int wK = idx >> 6, wCol = (idx & 63) * 4;
        pw[i] = *(const float4*)(Amat + (size_t)wK * RDIM + wCol);
    }

    for (int kt = 0; kt < 32; ++kt) {
        sI[iK + 0][iRow] = pi.x;
        sI[iK + 1][iRow] = pi.y;
        sI[iK + 2][iRow] = pi.z;
        sI[iK + 3][iRow] = pi.w;
#pragma unroll
        for (int i = 0; i < 4; ++i) {
            const int idx = tid + i * 256;
            const int wK = idx >> 6, wCol = (idx & 63) * 4;
            *(float4*)&sW[wK][wCol] = pw[i];
        }
        __syncthreads();

        if (kt + 1 < 32) {
            const int kn = kt + 1;
            const float* IN = (kn & 16) ? XP : H;
            const float* W  = (kn & 16) ? Bmat : Amat;
            const int k0 = (kn & 15) * 16;
            pi = *(const float4*)(IN + (size_t)(row0 + iRow) * RDIM + k0 + iK);
#pragma unroll
            for (int i = 0; i < 4; ++i) {
                const int idx = tid + i * 256;
                const int wK = idx >> 6, wCol = (idx & 63) * 4;
                pw[i] = *(const float4*)(W + (size_t)(k0 + wK) * RDIM + wCol);
            }
        }

#pragma unroll
        for (int kk = 0; kk < 16; ++kk) {
            float a[8], b[8];
            *(float4*)&a[0] = *(const float4*)&sI[kk][mBase];
            *(float4*)&a[4] = *(const float4*)&sI[kk][mBase + 4];
            *(float4*)&b[0] = *(const float4*)&sW[kk][nBase];
            *(float4*)&b[4] = *(const float4*)&sW[kk][nBase + 4];
#pragma unroll
            for (int i = 0; i < 8; ++i)
#pragma unroll
                for (int j = 0; j < 8; ++j)
                    acc[i][j] = fmaf(a[i], b[j], acc[i][j]);
        }
        __syncthreads();
    }

    // epilogue: all global XP reads for this block completed before last barrier
    float4 t0 = *(const float4*)(tau + nBase);
    float4 t1 = *(const float4*)(tau + nBase + 4);
    float tv[8] = {t0.x, t0.y, t0.z, t0.w, t1.x, t1.y, t1.z, t1.w};
#pragma unroll
    for (int i = 0; i < 8; ++i) {
        const int r = row0 + mBase + i;
        float4 h0 = *(const float4*)(H + (size_t)r * RDIM + nBase);
        float4 h1 = *(const float4*)(H + (size_t)r * RDIM + nBase + 4);
        float hv[8] = {h0.x, h0.y, h0.z, h0.w, h1.x, h1.y, h1.z, h1.w};
        float o[8];
#pragma unroll
        for (int j = 0; j < 8; ++j) {
            const float dhdt = -hv[j] / tv[j] + tanhf(acc[i][j]);
            o[j] = hv[j] + 0.1f * dhdt;
        }
        *(float4*)(XP + (size_t)r * RDIM + nBase)     = *(float4*)&o[0];
        *(float4*)(XP + (size_t)r * RDIM + nBase + 4) = *(float4*)&o[4];
    }
}

// ---------------------------------------------------------------------------
// Kernel 3: logits = h_new@Wg + bg ; +0.1 at prev_sel (set semantics);
// top-2 + softmax; writes idx (as float) then weights.
// Block = 64 rows, Wg & h_new k-chunked (64) through LDS.
// ---------------------------------------------------------------------------
__global__ __launch_bounds__(256) void k_logits(
    const float* __restrict__ HN, const float* __restrict__ Wg,
    const float* __restrict__ bg, const int* __restrict__ PS,
    float* __restrict__ OUT)
{
    __shared__ float sWg[64 * 64];   // chunk [k][e], pitch 64
    __shared__ float sT[64 * 65];    // ht chunk [k][r] pitch 65 / logits [r][e] pitch 65
    const int tid  = threadIdx.x;
    const int row0 = blockIdx.x * 64;
    const int rg = tid >> 4, eg = tid & 15;   // rows rg*4.., cols eg*4..

    float acc[4][4];
#pragma unroll
    for (int i = 0; i < 4; ++i)
#pragma unroll
        for (int j = 0; j < 4; ++j) acc[i][j] = 0.0f;

    for (int kc = 0; kc < RDIM; kc += 64) {
        __syncthreads();   // previous chunk fully consumed
        // stage Wg chunk: contiguous 16KB
#pragma unroll
        for (int i = 0; i < 4; ++i) {
            const int idx4 = (tid + i * 256) * 4;
            *(float4*)&sWg[idx4] = *(const float4*)(Wg + kc * EDIM + idx4);
        }
        // stage h_new chunk transposed: [k][r] pitch 65
#pragma unroll
        for (int i = 0; i < 4; ++i) {
            const int idx = tid + i * 256;
            const int r  = idx >> 4;
            const int kq = (idx & 15) * 4;
            float4 v = *(const float4*)(HN + (size_t)(row0 + r) * RDIM + kc + kq);
            sT[(kq + 0) * 65 + r] = v.x;
            sT[(kq + 1) * 65 + r] = v.y;
            sT[(kq + 2) * 65 + r] = v.z;
            sT[(kq + 3) * 65 + r] = v.w;
        }
        __syncthreads();

        for (int k = 0; k < 64; ++k) {
            float a[4], b[4];
            a[0] = sT[k * 65 + rg * 4 + 0];
            a[1] = sT[k * 65 + rg * 4 + 1];
            a[2] = sT[k * 65 + rg * 4 + 2];
            a[3] = sT[k * 65 + rg * 4 + 3];
            *(float4*)&b[0] = *(const float4*)&sWg[k * 64 + eg * 4];
#pragma unroll
            for (int i = 0; i < 4; ++i)
#pragma unroll
                for (int j = 0; j < 4; ++j)
                    acc[i][j] = fmaf(a[i], b[j], acc[i][j]);
        }
    }

    __syncthreads();
    // write logits (+bg) into sT as [r][e] pitch 65
    float bgv[4];
#pragma unroll
    for (int j = 0; j < 4; ++j) bgv[j] = bg[eg * 4 + j];
#pragma unroll
    for (int i = 0; i < 4; ++i)
#pragma unroll
        for (int j = 0; j < 4; ++j)
            sT[(rg * 4 + i) * 65 + eg * 4 + j] = acc[i][j] + bgv[j];
    __syncthreads();

    if (tid < 64) {
        const int r = tid;
        const int grow = row0 + r;
        const int e0 = PS[grow * 2 + 0];
        const int e1 = PS[grow * 2 + 1];
        float v1 = -3.4e38f, v2 = -3.4e38f;
        int i1 = 0, i2 = 0;
        for (int e = 0; e < 64; ++e) {
            float v = sT[r * 65 + e];
            if (e == e0 || e == e1) v += 0.1f;   // set-then-add: 0.1 once even if dup
            if (v > v1) { v2 = v1; i2 = i1; v1 = v; i1 = e; }
            else if (v > v2) { v2 = v; i2 = e; }
        }
        const float ex  = expf(v2 - v1);
        const float inv = 1.0f / (1.0f + ex);
        OUT[grow * 2 + 0] = (float)i1;
        OUT[grow * 2 + 1] = (float)i2;
        OUT[OUT_W_OFF + grow * 2 + 0] = inv;
        OUT[OUT_W_OFF + grow * 2 + 1] = ex * inv;
    }
}

// ---------------------------------------------------------------------------
extern "C" void kernel_launch(void* const* d_in, const int* in_sizes, int n_in,
                              void* d_out, int out_size, void* d_ws, size_t ws_size,
                              hipStream_t stream)
{
    const float* x   = (const float*)d_in[0];
    const float* h   = (const float*)d_in[1];
    const int*   ps  = (const int*)d_in[2];
    const float* Wp  = (const float*)d_in[3];
    const float* bp  = (const float*)d_in[4];
    const float* tau = (const float*)d_in[5];
    const float* A   = (const float*)d_in[6];
    const float* Bm  = (const float*)d_in[7];
    const float* Wg  = (const float*)d_in[8];
    const float* bg  = (const float*)d_in[9];
    float* out = (float*)d_out;
    float* xp  = (float*)d_ws;   // [B, R] fp32 = 64 MB; becomes h_new in-place

    k_xproj <<<BDIM / 128, 512, 0, stream>>>(x, Wp, bp, xp);
    k_cfc   <<<BDIM / 64, 256, 0, stream>>>(h, A, Bm, tau, xp);
    k_logits<<<BDIM / 64, 256, 0, stream>>>(xp, Wg, bg, ps, out);
}